// Round 1
// 412.379 us; speedup vs baseline: 1.0584x; 1.0584x over previous
//
#include <hip/hip_runtime.h>
#include <hip/hip_bf16.h>

#define D_OUT 64
#define K_DIM 512
#define RPB 128            // rows per bucket (pow2)
#define RPB_SHIFT 7
#define EPB 8192           // edges per partition chunk
#define RCAP 3072          // record capacity per bucket (mean 2046, +22 sigma)

using short8  = __attribute__((ext_vector_type(8))) short;
using floatx4 = __attribute__((ext_vector_type(4))) float;

__device__ inline unsigned short f32_to_bf16(float f) {
    unsigned int u = __float_as_uint(f);
    u += 0x7FFFu + ((u >> 16) & 1u);   // round-to-nearest-even
    return (unsigned short)(u >> 16);
}

__device__ inline float bf16lo_f32(unsigned int g) {   // low ushort -> f32
    return __uint_as_float(g << 16);
}
__device__ inline float bf16hi_f32(unsigned int g) {   // high ushort -> f32
    return __uint_as_float(g & 0xFFFF0000u);
}

// ---------------------------------------------------------------------------
// Wt[n][k] = bf16(W[k][n]) : 64 x 512 bf16 (64 KB, L2-resident)
__global__ void wt_kernel(const float* __restrict__ W, unsigned short* __restrict__ wt) {
    int i = blockIdx.x * blockDim.x + threadIdx.x;
    if (i < D_OUT * K_DIM) {
        int n = i >> 9;
        int k = i & 511;
        wt[i] = f32_to_bf16(W[k * D_OUT + n]);
    }
}

// ---------------------------------------------------------------------------
// gemm v4: as v3 but H stored as bf16 (halves store traffic; enables packed
// 4-edges-per-load gather in sort_agg).
__global__ __launch_bounds__(256) void gemm_kernel(
    const float* __restrict__ A, const unsigned short* __restrict__ wt,
    unsigned short* __restrict__ H, int n) {
    const int tid  = threadIdx.x;
    const int wv   = tid >> 6;
    const int lane = tid & 63;
    const int ln   = lane & 15;
    const int quad = lane >> 4;
    const int row0 = blockIdx.x * 64 + wv * 16;

    int arow = row0 + ln;
    if (arow >= n) arow = n - 1;          // clamp (stores guarded)
    const float* Arow = A + (size_t)arow * K_DIM;
    const unsigned short* wb = wt + (size_t)ln * K_DIM;

    floatx4 acc0 = {0.f, 0.f, 0.f, 0.f};
    floatx4 acc1 = {0.f, 0.f, 0.f, 0.f};
    floatx4 acc2 = {0.f, 0.f, 0.f, 0.f};
    floatx4 acc3 = {0.f, 0.f, 0.f, 0.f};

    for (int h0 = 0; h0 < K_DIM; h0 += 128) {
        // issue all 8 A-loads for this 128-k chunk (independent, batched)
        float4 t[8];
#pragma unroll
        for (int s = 0; s < 4; s++) {
            t[2 * s]     = *reinterpret_cast<const float4*>(Arow + h0 + s * 32 + quad * 8);
            t[2 * s + 1] = *reinterpret_cast<const float4*>(Arow + h0 + s * 32 + quad * 8 + 4);
        }
        // convert to bf16 fragments
        short8 ab[4];
#pragma unroll
        for (int s = 0; s < 4; s++) {
            float4 a0 = t[2 * s], a1 = t[2 * s + 1];
            short8 af;
            af[0] = (short)f32_to_bf16(a0.x);
            af[1] = (short)f32_to_bf16(a0.y);
            af[2] = (short)f32_to_bf16(a0.z);
            af[3] = (short)f32_to_bf16(a0.w);
            af[4] = (short)f32_to_bf16(a1.x);
            af[5] = (short)f32_to_bf16(a1.y);
            af[6] = (short)f32_to_bf16(a1.z);
            af[7] = (short)f32_to_bf16(a1.w);
            ab[s] = af;
        }
        // MFMA over the 4 k-steps (B from L2-hot Wt)
#pragma unroll
        for (int s = 0; s < 4; s++) {
            const int ko = h0 + s * 32 + quad * 8;
            short8 b0 = *reinterpret_cast<const short8*>(wb + ko);
            short8 b1 = *reinterpret_cast<const short8*>(wb + 16 * K_DIM + ko);
            short8 b2 = *reinterpret_cast<const short8*>(wb + 32 * K_DIM + ko);
            short8 b3 = *reinterpret_cast<const short8*>(wb + 48 * K_DIM + ko);
            acc0 = __builtin_amdgcn_mfma_f32_16x16x32_bf16(ab[s], b0, acc0, 0, 0, 0);
            acc1 = __builtin_amdgcn_mfma_f32_16x16x32_bf16(ab[s], b1, acc1, 0, 0, 0);
            acc2 = __builtin_amdgcn_mfma_f32_16x16x32_bf16(ab[s], b2, acc2, 0, 0, 0);
            acc3 = __builtin_amdgcn_mfma_f32_16x16x32_bf16(ab[s], b3, acc3, 0, 0, 0);
        }
    }

    // C/D layout: col = lane&15, row = quad*4 + reg  [m89]
#pragma unroll
    for (int r = 0; r < 4; r++) {
        int gr = row0 + quad * 4 + r;
        if (gr < n) {
            unsigned short* Hr = H + (size_t)gr * D_OUT;
            Hr[ln]      = f32_to_bf16(acc0[r]);
            Hr[16 + ln] = f32_to_bf16(acc1[r]);
            Hr[32 + ln] = f32_to_bf16(acc2[r]);
            Hr[48 + ln] = f32_to_bf16(acc3[r]);
        }
    }
}

// ---------------------------------------------------------------------------
// P1: per-(chunk, bucket) histogram.  counts[b * nb + blk]
__global__ __launch_bounds__(256) void count_kernel(
    const int* __restrict__ rows, int* __restrict__ counts,
    int E, int nbuck, int nb) {
    extern __shared__ int cnt[];
    const int tid = threadIdx.x, blk = blockIdx.x;
    for (int b = tid; b < nbuck; b += 256) cnt[b] = 0;
    __syncthreads();
    const int base = blk * EPB;
#pragma unroll
    for (int i = 0; i < EPB / 256; i++) {
        int e = base + tid + i * 256;
        if (e < E) atomicAdd(&cnt[rows[e] >> RPB_SHIFT], 1);
    }
    __syncthreads();
    for (int b = tid; b < nbuck; b += 256) counts[b * nb + blk] = cnt[b];
}

// ---------------------------------------------------------------------------
// 3-phase scan (1024 elements / block)
__global__ __launch_bounds__(256) void scan1_kernel(
    const int* __restrict__ counts, int* __restrict__ bsum, int n) {
    __shared__ int wsh[4];
    const int tid = threadIdx.x, lane = tid & 63, wid = tid >> 6;
    int i0 = blockIdx.x * 1024 + tid * 4;
    int s = 0;
#pragma unroll
    for (int j = 0; j < 4; j++) {
        int ix = i0 + j;
        s += (ix < n) ? counts[ix] : 0;
    }
#pragma unroll
    for (int d = 32; d; d >>= 1) s += __shfl_xor(s, d, 64);
    if (lane == 0) wsh[wid] = s;
    __syncthreads();
    if (tid == 0) bsum[blockIdx.x] = wsh[0] + wsh[1] + wsh[2] + wsh[3];
}

__global__ __launch_bounds__(1024) void scan2_kernel(
    const int* __restrict__ bsum, int* __restrict__ bbase,
    int* __restrict__ scanned, int nblk, int L, int E) {
    __shared__ int wsum[16];
    const int tid = threadIdx.x, lane = tid & 63, wid = tid >> 6;
    int v = (tid < nblk) ? bsum[tid] : 0;
    int x = v;
#pragma unroll
    for (int d = 1; d < 64; d <<= 1) {
        int y = __shfl_up(x, d, 64);
        if (lane >= d) x += y;
    }
    if (lane == 63) wsum[wid] = x;
    __syncthreads();
    if (tid < 16) {
        int w = wsum[tid];
        int xx = w;
#pragma unroll
        for (int d = 1; d < 16; d <<= 1) {
            int y = __shfl_up(xx, d, 64);
            if (tid >= d) xx += y;
        }
        wsum[tid] = xx - w;
    }
    __syncthreads();
    if (tid < nblk) bbase[tid] = wsum[wid] + (x - v);
    if (tid == 0) scanned[L] = E;
}

__global__ __launch_bounds__(256) void scan3_kernel(
    const int* __restrict__ counts, const int* __restrict__ bbase,
    int* __restrict__ scanned, int n) {
    __shared__ int wsum[4];
    const int tid = threadIdx.x, lane = tid & 63, wid = tid >> 6;
    const int i0 = blockIdx.x * 1024 + tid * 4;
    int v[4];
#pragma unroll
    for (int j = 0; j < 4; j++) {
        int ix = i0 + j;
        v[j] = (ix < n) ? counts[ix] : 0;
    }
#pragma unroll
    for (int j = 1; j < 4; j++) v[j] += v[j - 1];
    int t = v[3];
    int x = t;
#pragma unroll
    for (int d = 1; d < 64; d <<= 1) {
        int y = __shfl_up(x, d, 64);
        if (lane >= d) x += y;
    }
    if (lane == 63) wsum[wid] = x;
    __syncthreads();
    if (tid == 0) {
        int a = 0;
#pragma unroll
        for (int w = 0; w < 4; w++) { int tmp = wsum[w]; wsum[w] = a; a += tmp; }
    }
    __syncthreads();
    int excl = bbase[blockIdx.x] + wsum[wid] + (x - t);
#pragma unroll
    for (int j = 0; j < 4; j++) {
        int ix = i0 + j;
        if (ix < n) scanned[ix] = excl + ((j == 0) ? 0 : v[j - 1]);
    }
}

// ---------------------------------------------------------------------------
// P3: partition edges into bucket-grouped packed records (col | rl<<17, val).
__global__ __launch_bounds__(256) void partition_kernel(
    const int* __restrict__ rows, const int* __restrict__ cols,
    const float* __restrict__ vals, const int* __restrict__ scanned,
    int2* __restrict__ keys, int E, int nbuck, int nb) {
    extern __shared__ int offs[];
    const int tid = threadIdx.x, blk = blockIdx.x;
    for (int b = tid; b < nbuck; b += 256) offs[b] = scanned[b * nb + blk];
    __syncthreads();
    const int base = blk * EPB;
#pragma unroll
    for (int i = 0; i < EPB / 256; i++) {
        int e = base + tid + i * 256;
        if (e < E) {
            int r = rows[e];
            int c = cols[e];
            float v = vals[e];
            int b = r >> RPB_SHIFT;
            int p = atomicAdd(&offs[b], 1);
            keys[p] = make_int2(c | ((r & (RPB - 1)) << 17), __float_as_int(v));
        }
    }
}

// ---------------------------------------------------------------------------
// P4: one block per bucket. LDS counting sort by row-local, then wave-per-row
// register accumulation. h is bf16: a wave gathers FOUR edges per load
// (16 lanes/edge, uint2 = 4 bf16 cols/lane; 128 B = one cache line per edge).
__global__ __launch_bounds__(512) void sort_agg_kernel(
    const unsigned short* __restrict__ h, const int2* __restrict__ keys,
    const int* __restrict__ scanned, float* __restrict__ out,
    int N, int nb) {
    __shared__ int2 rec[RCAP];
    __shared__ int cnt[RPB];
    __shared__ int excl[RPB];
    __shared__ int cur[RPB];
    __shared__ int wtot[2];

    const int tid  = threadIdx.x;
    const int lane = tid & 63;
    const int wv   = tid >> 6;           // 0..7
    const int q    = lane >> 4;          // 0..3  : edge slot within wave
    const int li   = lane & 15;          // 0..15 : 4 cols per lane
    const int b    = blockIdx.x;

    const int start = scanned[b * nb];
    const int end   = scanned[(b + 1) * nb];
    const int m     = end - start;

    if (tid < RPB) cnt[tid] = 0;
    __syncthreads();

    // count rows
    for (int i = tid; i < m; i += 512) {
        int rl = keys[start + i].x >> 17;
        atomicAdd(&cnt[rl], 1);
    }
    __syncthreads();

    // exclusive scan of 128 counters (2 waves)
    int v = 0, x = 0;
    if (tid < RPB) {
        v = cnt[tid];
        x = v;
#pragma unroll
        for (int d = 1; d < 64; d <<= 1) {
            int y = __shfl_up(x, d, 64);
            if (lane >= d) x += y;
        }
        if (lane == 63) wtot[tid >> 6] = x;
    }
    __syncthreads();
    if (tid < RPB) {
        int base = (tid >= 64) ? wtot[0] : 0;
        int ex = base + x - v;
        excl[tid] = ex;
        cur[tid]  = ex;
    }
    __syncthreads();

    // scatter into row-sorted LDS positions
    for (int i = tid; i < m; i += 512) {
        int2 kv = keys[start + i];
        int rl = kv.x >> 17;
        int p = atomicAdd(&cur[rl], 1);
        if (p < RCAP) rec[p] = kv;
    }
    __syncthreads();

    // aggregate: wave per row; 4 edges per load instruction, 8 in flight.
    const int row0 = b * RPB;
    for (int rl = wv; rl < RPB; rl += 8) {
        int s = excl[rl];
        int e = cur[rl];                 // = excl + count
        float4 acc = {0.f, 0.f, 0.f, 0.f};
        int j = s;
        for (; j + 8 <= e; j += 8) {
            int2 kA = rec[j + q];
            int2 kB = rec[j + 4 + q];
            const uint2 gA = *reinterpret_cast<const uint2*>(
                h + (size_t)(kA.x & 0x1FFFF) * D_OUT + li * 4);
            const uint2 gB = *reinterpret_cast<const uint2*>(
                h + (size_t)(kB.x & 0x1FFFF) * D_OUT + li * 4);
            float vA = __int_as_float(kA.y);
            float vB = __int_as_float(kB.y);
            acc.x += vA * bf16lo_f32(gA.x);
            acc.y += vA * bf16hi_f32(gA.x);
            acc.z += vA * bf16lo_f32(gA.y);
            acc.w += vA * bf16hi_f32(gA.y);
            acc.x += vB * bf16lo_f32(gB.x);
            acc.y += vB * bf16hi_f32(gB.x);
            acc.z += vB * bf16lo_f32(gB.y);
            acc.w += vB * bf16hi_f32(gB.y);
        }
        for (; j < e; j += 4) {
            bool on = (j + q) < e;
            int2 kv = rec[on ? j + q : j];     // j < e, so rec[j] is safe
            const uint2 g = *reinterpret_cast<const uint2*>(
                h + (size_t)(kv.x & 0x1FFFF) * D_OUT + li * 4);
            float vv = on ? __int_as_float(kv.y) : 0.f;
            acc.x += vv * bf16lo_f32(g.x);
            acc.y += vv * bf16hi_f32(g.x);
            acc.z += vv * bf16lo_f32(g.y);
            acc.w += vv * bf16hi_f32(g.y);
        }
        // combine the 4 edge slots (xor 16, then 32)
        acc.x += __shfl_xor(acc.x, 16, 64);
        acc.y += __shfl_xor(acc.y, 16, 64);
        acc.z += __shfl_xor(acc.z, 16, 64);
        acc.w += __shfl_xor(acc.w, 16, 64);
        acc.x += __shfl_xor(acc.x, 32, 64);
        acc.y += __shfl_xor(acc.y, 32, 64);
        acc.z += __shfl_xor(acc.z, 32, 64);
        acc.w += __shfl_xor(acc.w, 32, 64);

        int gr = row0 + rl;
        if (gr < N && q == 0) {
            float4 o;
            o.x = fmaxf(acc.x, 0.f);
            o.y = fmaxf(acc.y, 0.f);
            o.z = fmaxf(acc.z, 0.f);
            o.w = fmaxf(acc.w, 0.f);
            *reinterpret_cast<float4*>(out + (size_t)gr * D_OUT + li * 4) = o;
        }
    }
}

// ---------------------------------------------------------------------------
extern "C" void kernel_launch(void* const* d_in, const int* in_sizes, int n_in,
                              void* d_out, int out_size, void* d_ws, size_t ws_size,
                              hipStream_t stream) {
    const float* A    = (const float*)d_in[0];
    const float* W    = (const float*)d_in[1];
    const float* vals = (const float*)d_in[2];
    const int*   rows = (const int*)d_in[3];
    const int*   cols = (const int*)d_in[4];
    float* out = (float*)d_out;

    const int N = out_size / D_OUT;                 // 100000
    const int E = in_sizes[2];                      // 1600000
    const int nbuck = (N + RPB - 1) >> RPB_SHIFT;   // 782
    const int nb = (E + EPB - 1) / EPB;             // 196
    const int L = nbuck * nb;                       // 153272
    const int SB = (L + 1023) / 1024;               // 150

    // workspace layout (keys 8-aligned; h is bf16 now)
    char* ws = (char*)d_ws;
    unsigned short* h       = (unsigned short*)ws;                        // N*64 bf16
    int2*           keys    = (int2*)(ws + (size_t)N * D_OUT * 2);        // E int2
    unsigned short* wt      = (unsigned short*)((char*)keys + (size_t)E * 8);
    int*            counts  = (int*)((char*)wt + (size_t)D_OUT * K_DIM * 2); // L
    int*            scanned = counts + L;                                 // L+1
    int*            bsum    = scanned + L + 1;                            // SB
    int*            bbase   = bsum + SB;                                  // SB

    const size_t cnt_lds = (size_t)nbuck * 4;

    wt_kernel<<<(D_OUT * K_DIM + 255) / 256, 256, 0, stream>>>(W, wt);
    gemm_kernel<<<(N + 63) / 64, 256, 0, stream>>>(A, wt, h, N);
    count_kernel<<<nb, 256, cnt_lds, stream>>>(rows, counts, E, nbuck, nb);
    scan1_kernel<<<SB, 256, 0, stream>>>(counts, bsum, L);
    scan2_kernel<<<1, 1024, 0, stream>>>(bsum, bbase, scanned, SB, L, E);
    scan3_kernel<<<SB, 256, 0, stream>>>(counts, bbase, scanned, L);
    partition_kernel<<<nb, 256, cnt_lds, stream>>>(rows, cols, vals, scanned, keys, E, nbuck, nb);
    sort_agg_kernel<<<nbuck, 512, 0, stream>>>(h, keys, scanned, out, N, nb);
}